// Round 3
// baseline (336.509 us; speedup 1.0000x reference)
//
#include <hip/hip_runtime.h>
#include <hip/hip_fp16.h>

// Problem constants (B=4, S=8192, IN=OUT=1024, GROUP=128)
#define K_DIM 1024
#define N_DIM 1024

typedef int v4i __attribute__((ext_vector_type(4)));

__device__ __forceinline__ void async_load16(const void* g, void* l) {
    __builtin_amdgcn_global_load_lds(
        (const __attribute__((address_space(1))) unsigned int*)g,
        (__attribute__((address_space(3))) unsigned int*)l,
        16, 0, 0);
}

// ---------------- Kernel A: weight prep (unchanged, verified R1/R2) --------
__global__ __launch_bounds__(256) void prep_w(const float* __restrict__ w,
                                              signed char* __restrict__ wq,
                                              float* __restrict__ wscale) {
    const int lane = threadIdx.x & 63;
    const int row  = blockIdx.x * 4 + (threadIdx.x >> 6);
    const float4* wr = (const float4*)(w + (size_t)row * K_DIM);
    float4 v[4];
#pragma unroll
    for (int j = 0; j < 4; ++j) v[j] = wr[lane * 4 + j];

    float g = 0.f;
#pragma unroll
    for (int j = 0; j < 4; ++j) {
        g = fmaxf(g, fabsf(v[j].x)); g = fmaxf(g, fabsf(v[j].y));
        g = fmaxf(g, fabsf(v[j].z)); g = fmaxf(g, fabsf(v[j].w));
    }
    g = fmaxf(g, __shfl_xor(g, 1, 64));
    g = fmaxf(g, __shfl_xor(g, 2, 64));
    g = fmaxf(g, __shfl_xor(g, 4, 64));
    const float s = __half2float(__float2half(fmaxf(g, 1e-8f)));
    float t = s;
    t += __shfl_xor(t, 8, 64);
    t += __shfl_xor(t, 16, 64);
    t += __shfl_xor(t, 32, 64);
    if (lane == 0) wscale[row] = t * 0.125f;

    int pk[4];
#pragma unroll
    for (int j = 0; j < 4; ++j) {
        const int b0 = (v[j].x > 0.f) ? 1 : -1;
        const int b1 = (v[j].y > 0.f) ? 1 : -1;
        const int b2 = (v[j].z > 0.f) ? 1 : -1;
        const int b3 = (v[j].w > 0.f) ? 1 : -1;
        pk[j] = (b0 & 255) | ((b1 & 255) << 8) | ((b2 & 255) << 16) | (b3 << 24);
    }
    *(int4*)(wq + (size_t)row * K_DIM + lane * 16) = make_int4(pk[0], pk[1], pk[2], pk[3]);
}

// ---------------- Fused quant + int8 GEMM ----------------
// One block per 128-token band (grid = 256 = 1 block/CU). Phase 1 quantizes
// x into a 128KB LDS A-tile (swizzled: phys 16B-chunk = chunk ^ (row&7)).
// Phase 2 hoists all A fragments into registers (256 VGPR/wave; 1 block/CU
// means the full 512-VGPR budget is ours), then loops 8 n-tiles with B
// double-buffered via global_load_lds (BK=64, 2x8KB) from L2-resident wq.
// K-loop LDS traffic is B-only: 16KB/stage vs 32-48KB in the split kernel.
__global__ __launch_bounds__(256, 1) void fused_qgemm(
        const float* __restrict__ x,
        const signed char* __restrict__ wq,
        const float* __restrict__ wscale,
        const float* __restrict__ bias,
        float* __restrict__ out) {
    __shared__ __align__(16) signed char As[128 * 1024];    // 128 KB
    __shared__ __align__(16) signed char Bsm[2][128 * 64];  // 2 x 8 KB
    __shared__ float xsL[128];                              // per-token scales

    const int tid  = threadIdx.x;
    const int lane = tid & 63;
    const int wave = tid >> 6;
    const int wm = wave >> 1, wn = wave & 1;
    const size_t mBase = (size_t)blockIdx.x * 128;

    // ---- Phase 1: per-token quant into LDS (wave w -> rows 32w..32w+31) ----
    for (int r = 0; r < 32; ++r) {
        const int row = wave * 32 + r;
        const float4* xr = (const float4*)(x + (mBase + row) * K_DIM);
        float4 v[4];
#pragma unroll
        for (int j = 0; j < 4; ++j) v[j] = xr[lane * 4 + j];  // 16 consecutive floats
        float am = 0.f;
#pragma unroll
        for (int j = 0; j < 4; ++j) {
            am = fmaxf(am, fabsf(v[j].x)); am = fmaxf(am, fabsf(v[j].y));
            am = fmaxf(am, fabsf(v[j].z)); am = fmaxf(am, fabsf(v[j].w));
        }
#pragma unroll
        for (int off = 32; off >= 1; off >>= 1) am = fmaxf(am, __shfl_xor(am, off, 64));
        const float scale = fmaxf(am, 1e-8f) / 127.f;
        const float inv   = 1.0f / scale;          // same math as R2 (passed)
        int pk[4];
#pragma unroll
        for (int j = 0; j < 4; ++j) {
            const int b0 = (int)fminf(fmaxf(rintf(v[j].x * inv), -128.f), 127.f);
            const int b1 = (int)fminf(fmaxf(rintf(v[j].y * inv), -128.f), 127.f);
            const int b2 = (int)fminf(fmaxf(rintf(v[j].z * inv), -128.f), 127.f);
            const int b3 = (int)fminf(fmaxf(rintf(v[j].w * inv), -128.f), 127.f);
            pk[j] = (b0 & 255) | ((b1 & 255) << 8) | ((b2 & 255) << 16) | (b3 << 24);
        }
        // lane owns logical chunk `lane`; swizzled placement chunk^(row&7)
        *(int4*)(As + row * 1024 + ((lane ^ (row & 7)) << 4)) =
            make_int4(pk[0], pk[1], pk[2], pk[3]);
        if (lane == 0) xsL[row] = scale;
    }
    __syncthreads();

    // ---- A fragments -> registers (full K: 4 mt x 16 ks, one-time) ----
    const int r16 = lane & 15, g = lane >> 4, x7 = lane & 7;
    v4i areg[4][16];
#pragma unroll
    for (int mt = 0; mt < 4; ++mt) {
        const signed char* Ab = As + (wm * 64 + mt * 16 + r16) * 1024;
#pragma unroll
        for (int s = 0; s < 16; ++s)
            areg[mt][s] = *(const v4i*)(Ab + (((s * 4 + g) ^ x7) << 4));
    }
    const int rq = g * 4;
    float xsr[4][4];
#pragma unroll
    for (int mt = 0; mt < 4; ++mt)
#pragma unroll
        for (int i = 0; i < 4; ++i)
            xsr[mt][i] = xsL[wm * 64 + mt * 16 + rq + i];

    // ---- B staging setup ----
    // thread t stages 2x16B: stage rows c*64 + (t>>2), phys chunk t&3;
    // fetch the PERMUTED global chunk so LDS dest stays base + tid*16.
    const size_t bOff = (size_t)(tid >> 2) * K_DIM + (((tid & 3) ^ ((tid >> 3) & 3)) << 4);
    int bfo[4];
#pragma unroll
    for (int nt4 = 0; nt4 < 4; ++nt4) {
        const int rowb = wn * 64 + nt4 * 16 + r16;
        bfo[nt4] = rowb * 64 + ((g ^ ((rowb >> 1) & 3)) << 4);  // swizzled
    }

    // prologue: stage S=0 (nt=0, s=0) into buffer 0
    {
        const signed char* src = wq + bOff;
        async_load16(src,         Bsm[0] + tid * 16);
        async_load16(src + 65536, Bsm[0] + 4096 + tid * 16);
    }
    __syncthreads();

    const int cc = lane & 15;
    for (int nt = 0; nt < 8; ++nt) {
        v4i acc[4][4] = {};
#pragma unroll
        for (int s = 0; s < 16; ++s) {
            const int S = nt * 16 + s;
            if (S < 127) {  // prefetch S+1 into the other buffer (in flight during compute)
                const int Sn = S + 1;
                const signed char* src = wq + (size_t)(Sn >> 4) * (128 * K_DIM)
                                            + (size_t)(Sn & 15) * 64 + bOff;
                signed char* dst = Bsm[Sn & 1] + tid * 16;
                async_load16(src,         dst);
                async_load16(src + 65536, dst + 4096);
            }
            const signed char* bb = Bsm[s & 1];
            v4i bf[4];
#pragma unroll
            for (int nt4 = 0; nt4 < 4; ++nt4)
                bf[nt4] = *(const v4i*)(bb + bfo[nt4]);
#pragma unroll
            for (int mt = 0; mt < 4; ++mt)
#pragma unroll
                for (int nt4 = 0; nt4 < 4; ++nt4)
                    acc[mt][nt4] = __builtin_amdgcn_mfma_i32_16x16x64_i8(
                        areg[mt][s], bf[nt4], acc[mt][nt4], 0, 0, 0);
            __syncthreads();  // drains this stage's reads + next stage's loads
        }
        // ---- epilogue for this n-tile (stores overlap next n-tile compute) ----
#pragma unroll
        for (int nt4 = 0; nt4 < 4; ++nt4) {
            const int col  = nt * 128 + wn * 64 + nt4 * 16 + cc;
            const float wsc = wscale[col];
            const float bbv = bias[col];
#pragma unroll
            for (int mt = 0; mt < 4; ++mt)
#pragma unroll
                for (int i = 0; i < 4; ++i)
                    out[(mBase + wm * 64 + mt * 16 + rq + i) * N_DIM + col] =
                        (float)acc[mt][nt4][i] * xsr[mt][i] * wsc + bbv;
        }
    }
}

extern "C" void kernel_launch(void* const* d_in, const int* in_sizes, int n_in,
                              void* d_out, int out_size, void* d_ws, size_t ws_size,
                              hipStream_t stream) {
    const float* x    = (const float*)d_in[0];
    const float* w    = (const float*)d_in[1];
    const float* bias = (const float*)d_in[2];
    float* out = (float*)d_out;

    const int BT = in_sizes[0] / K_DIM;  // 32768 tokens

    char* ws = (char*)d_ws;
    signed char* wq     = (signed char*)ws;                             // 1 MB
    float*       wscale = (float*)(ws + (size_t)N_DIM * K_DIM);         // 4 KB

    prep_w<<<N_DIM / 4, 256, 0, stream>>>(w, wq, wscale);
    fused_qgemm<<<BT / 128, 256, 0, stream>>>(x, wq, wscale, bias, out);
}